// Round 1
// baseline (249.979 us; speedup 1.0000x reference)
//
#include <hip/hip_runtime.h>

#define TOKENS 4096
#define HDIM   1024
#define EDIM   8
#define CAP    1536

// ---------------- GEMM1: h = relu(X @ W1 + b1) ----------------
// X: (4096,1024) row-major, W1: (1024,1024) row-major, h: (4096,1024)
#define BM 64
#define BN 64
#define BK 16

__global__ __launch_bounds__(256) void gemm1_relu(
    const float* __restrict__ X, const float* __restrict__ W1,
    const float* __restrict__ b1, float* __restrict__ Hout)
{
    __shared__ float As[BK][BM + 4];   // [k][m], padded (conflict + 16B align)
    __shared__ float Bs[BK][BN];       // [k][n]
    const int K = HDIM, N = HDIM;
    const int tid  = threadIdx.x;
    const int tx   = tid & 15;         // n-subtile
    const int ty   = tid >> 4;         // m-subtile
    const int arow = tid >> 2;         // 0..63  (m within tile)
    const int acol = (tid & 3) << 2;   // 0,4,8,12 (k)
    const int brow = tid >> 4;         // 0..15  (k)
    const int bcol = (tid & 15) << 2;  // 0..60  (n)

    const float* Ab = X + (size_t)(blockIdx.y * BM) * K;
    const float* Bb = W1 + blockIdx.x * BN;

    float acc[4][4] = {};

    for (int k0 = 0; k0 < K; k0 += BK) {
        float4 av = *(const float4*)(Ab + (size_t)arow * K + k0 + acol);
        float4 bv = *(const float4*)(Bb + (size_t)(k0 + brow) * N + bcol);
        As[acol + 0][arow] = av.x;
        As[acol + 1][arow] = av.y;
        As[acol + 2][arow] = av.z;
        As[acol + 3][arow] = av.w;
        *(float4*)&Bs[brow][bcol] = bv;
        __syncthreads();
#pragma unroll
        for (int kk = 0; kk < BK; kk++) {
            float4 a4 = *(const float4*)&As[kk][ty << 2];
            float4 b4 = *(const float4*)&Bs[kk][tx << 2];
            float a[4] = {a4.x, a4.y, a4.z, a4.w};
            float b[4] = {b4.x, b4.y, b4.z, b4.w};
#pragma unroll
            for (int i = 0; i < 4; i++)
#pragma unroll
                for (int j = 0; j < 4; j++)
                    acc[i][j] = fmaf(a[i], b[j], acc[i][j]);
        }
        __syncthreads();
    }

    const int gm = blockIdx.y * BM + (ty << 2);
    const int gn = blockIdx.x * BN + (tx << 2);
    float4 bias = *(const float4*)(b1 + gn);
#pragma unroll
    for (int i = 0; i < 4; i++) {
        float4 o;
        o.x = fmaxf(acc[i][0] + bias.x, 0.f);
        o.y = fmaxf(acc[i][1] + bias.y, 0.f);
        o.z = fmaxf(acc[i][2] + bias.z, 0.f);
        o.w = fmaxf(acc[i][3] + bias.w, 0.f);
        *(float4*)(Hout + (size_t)(gm + i) * N + gn) = o;
    }
}

// ---------------- Router: logits, softmax, top-2, flags ----------------
// One wave (64 lanes) per token. W2: (1024,8) row-major.
__global__ __launch_bounds__(256) void router_k(
    const float* __restrict__ Hbuf, const float* __restrict__ W2,
    const float* __restrict__ b2, float* __restrict__ probs_out,
    int* __restrict__ e0a, int* __restrict__ e1a,
    float* __restrict__ p0a, float* __restrict__ p1a,
    int* __restrict__ flags)
{
    const int wave  = threadIdx.x >> 6;
    const int lane  = threadIdx.x & 63;
    const int token = (blockIdx.x << 2) + wave;

    const float* hrow = Hbuf + (size_t)token * HDIM;
    float acc[8] = {0, 0, 0, 0, 0, 0, 0, 0};
#pragma unroll
    for (int k = 0; k < HDIM / 64; k++) {
        const int hidx = lane + (k << 6);
        const float hv = hrow[hidx];
        float4 wa = *(const float4*)(W2 + hidx * 8);
        float4 wb = *(const float4*)(W2 + hidx * 8 + 4);
        acc[0] = fmaf(hv, wa.x, acc[0]);
        acc[1] = fmaf(hv, wa.y, acc[1]);
        acc[2] = fmaf(hv, wa.z, acc[2]);
        acc[3] = fmaf(hv, wa.w, acc[3]);
        acc[4] = fmaf(hv, wb.x, acc[4]);
        acc[5] = fmaf(hv, wb.y, acc[5]);
        acc[6] = fmaf(hv, wb.z, acc[6]);
        acc[7] = fmaf(hv, wb.w, acc[7]);
    }
#pragma unroll
    for (int off = 32; off; off >>= 1) {
#pragma unroll
        for (int e = 0; e < 8; e++) acc[e] += __shfl_xor(acc[e], off);
    }

    if (lane == 0) {
        float logit[8];
#pragma unroll
        for (int e = 0; e < 8; e++) logit[e] = acc[e] + b2[e];
        float mx = logit[0];
#pragma unroll
        for (int e = 1; e < 8; e++) mx = fmaxf(mx, logit[e]);
        float p[8], s = 0.f;
#pragma unroll
        for (int e = 0; e < 8; e++) { p[e] = expf(logit[e] - mx); s += p[e]; }
        const float inv = 1.f / s;
#pragma unroll
        for (int e = 0; e < 8; e++) p[e] *= inv;

        float4 pa = {p[0], p[1], p[2], p[3]};
        float4 pb = {p[4], p[5], p[6], p[7]};
        *(float4*)(probs_out + (size_t)token * 8)     = pa;
        *(float4*)(probs_out + (size_t)token * 8 + 4) = pb;

        // top-2, ties -> lower index (strict > keeps first max), matches lax.top_k
        int e0 = 0; float m0 = logit[0];
#pragma unroll
        for (int e = 1; e < 8; e++) if (logit[e] > m0) { m0 = logit[e]; e0 = e; }
        int e1 = -1; float m1 = -1e30f;
#pragma unroll
        for (int e = 0; e < 8; e++) if (e != e0 && logit[e] > m1) { m1 = logit[e]; e1 = e; }

        const float ps = p[e0] + p[e1];
        e0a[token] = e0;
        e1a[token] = e1;
        p0a[token] = p[e0] / ps;
        p1a[token] = p[e1] / ps;
        atomicOr(&flags[e0], 1);
    }
}

// ---------------- aux loss ----------------
__global__ __launch_bounds__(256) void aux_k(
    const float* __restrict__ probs, float* __restrict__ auxout)
{
    __shared__ float red[4][8];
    const int tid = threadIdx.x, lane = tid & 63, wave = tid >> 6;
    float acc[8] = {0, 0, 0, 0, 0, 0, 0, 0};
    for (int t = tid; t < TOKENS; t += 256) {
        float4 a = *(const float4*)(probs + (size_t)t * 8);
        float4 b = *(const float4*)(probs + (size_t)t * 8 + 4);
        acc[0] += a.x; acc[1] += a.y; acc[2] += a.z; acc[3] += a.w;
        acc[4] += b.x; acc[5] += b.y; acc[6] += b.z; acc[7] += b.w;
    }
#pragma unroll
    for (int off = 32; off; off >>= 1)
#pragma unroll
        for (int e = 0; e < 8; e++) acc[e] += __shfl_xor(acc[e], off);
    if (lane == 0)
#pragma unroll
        for (int e = 0; e < 8; e++) red[wave][e] = acc[e];
    __syncthreads();
    if (tid == 0) {
        float aux = 0.f;
#pragma unroll
        for (int e = 0; e < 8; e++) {
            float pe = (red[0][e] + red[1][e] + red[2][e] + red[3][e]) * (1.f / TOKENS);
            aux += pe * logf(pe * (float)EDIM + 1e-9f);
        }
        *auxout = aux;
    }
}

// ---------------- scatter dispatch/combine ----------------
__global__ __launch_bounds__(256) void scatter_k(
    const int* __restrict__ e0a, const int* __restrict__ e1a,
    const float* __restrict__ p0a, const float* __restrict__ p1a,
    const int* __restrict__ flags,
    float* __restrict__ dispatch, float* __restrict__ combine)
{
    const int t = blockIdx.x * 256 + threadIdx.x;
    if (t >= TOKENS) return;
    const int e0 = e0a[t], e1 = e1a[t];
    const size_t b0 = ((size_t)t * EDIM + e0) * CAP;      // slot 0 always
    dispatch[b0] = 1.f;
    combine[b0]  = p0a[t];
    const int s1 = flags[e1] ? 1 : 0;                     // slot depends on round-0 usage
    const size_t b1 = ((size_t)t * EDIM + e1) * CAP + s1;
    dispatch[b1] = 1.f;
    combine[b1]  = p1a[t];
}

extern "C" void kernel_launch(void* const* d_in, const int* in_sizes, int n_in,
                              void* d_out, int out_size, void* d_ws, size_t ws_size,
                              hipStream_t stream)
{
    const float* X  = (const float*)d_in[0];
    const float* W1 = (const float*)d_in[1];
    const float* b1 = (const float*)d_in[2];
    const float* W2 = (const float*)d_in[3];
    const float* b2 = (const float*)d_in[4];

    float* out = (float*)d_out;
    const size_t dispN = (size_t)TOKENS * EDIM * CAP;   // 50,331,648
    float* dispatch = out;
    float* combine  = out + dispN;
    float* probs    = out + 2 * dispN;
    float* auxout   = out + 2 * dispN + (size_t)TOKENS * EDIM;

    float* hbuf = (float*)d_ws;
    char* pp = (char*)d_ws + (size_t)TOKENS * HDIM * sizeof(float);
    int*   e0a = (int*)pp;   pp += TOKENS * sizeof(int);
    int*   e1a = (int*)pp;   pp += TOKENS * sizeof(int);
    float* p0a = (float*)pp; pp += TOKENS * sizeof(float);
    float* p1a = (float*)pp; pp += TOKENS * sizeof(float);
    int*   flags = (int*)pp;

    // zero dispatch+combine (harness poisons d_out once; we must produce zeros)
    hipMemsetAsync(dispatch, 0, 2 * dispN * sizeof(float), stream);
    hipMemsetAsync(flags, 0, EDIM * sizeof(int), stream);

    gemm1_relu<<<dim3(HDIM / BN, TOKENS / BM), 256, 0, stream>>>(X, W1, b1, hbuf);
    router_k<<<TOKENS / 4, 256, 0, stream>>>(hbuf, W2, b2, probs, e0a, e1a, p0a, p1a, flags);
    aux_k<<<1, 256, 0, stream>>>(probs, auxout);
    scatter_k<<<TOKENS / 256, 256, 0, stream>>>(e0a, e1a, p0a, p1a, flags, dispatch, combine);
}

// Round 3
// 190.913 us; speedup vs baseline: 1.3094x; 1.3094x over previous
//
#include <hip/hip_runtime.h>

#define TOKENS 4096
#define HDIM   1024
#define EDIM   8
#define CAP    1536

typedef float f32x4 __attribute__((ext_vector_type(4)));

// ---------------- GEMM1 fused with zero-fill of dispatch/combine ----------------
// X: (4096,1024) row-major, W1: (1024,1024) row-major, h: (4096,1024)
// Also streams 402 MB of zeros (dispatch+combine) via nontemporal stores
// interleaved with the FMA loop, so write-BW hides under fp32 compute.
#define BM 128
#define BN 64
#define BK 16
// zero-fill: 2*4096*8*1536 floats = 402,653,184 B / 512 blocks = 786,432 B
// = 49,152 float4 per block = 192 float4 per thread = 3 per k0-iteration.
#define ZF4_PER_BLOCK 49152

__global__ __launch_bounds__(256, 2) void gemm1_relu_fill(
    const float* __restrict__ X, const float* __restrict__ W1,
    const float* __restrict__ b1, float* __restrict__ Hout,
    float* __restrict__ zreg, int* __restrict__ flags)
{
    __shared__ float As[BK][BM + 4];   // stride 132 floats = 528 B (16B-aligned)
    __shared__ float Bs[BK][BN];
    const int K = HDIM, N = HDIM;
    const int tid  = threadIdx.x;
    const int arow = tid >> 1;          // 0..127
    const int acol = (tid & 1) << 3;    // 0 or 8
    const int brow = tid >> 4;          // 0..15
    const int bcol = (tid & 15) << 2;   // 0..60
    const int tx   = tid & 15;          // n: 16 x 4 = 64
    const int ty   = tid >> 4;          // m: 16 x 8 = 128

    const float* Ab = X  + (size_t)(blockIdx.y * BM) * K;
    const float* Bb = W1 + blockIdx.x * BN;

    const int blk = blockIdx.y * gridDim.x + blockIdx.x;   // 0..511
    if (blk == 0 && tid < EDIM) flags[tid] = 0;            // zero flags (used by router kernel)
    f32x4* Z = (f32x4*)zreg + (size_t)blk * ZF4_PER_BLOCK + tid;
    const f32x4 z4 = {0.f, 0.f, 0.f, 0.f};

    float acc[8][4] = {};
    int zs = 0;
    for (int k0 = 0; k0 < K; k0 += BK) {
        float4 a0 = *(const float4*)(Ab + (size_t)arow * K + k0 + acol);
        float4 a1 = *(const float4*)(Ab + (size_t)arow * K + k0 + acol + 4);
        float4 bv = *(const float4*)(Bb + (size_t)(k0 + brow) * N + bcol);
        As[acol + 0][arow] = a0.x;
        As[acol + 1][arow] = a0.y;
        As[acol + 2][arow] = a0.z;
        As[acol + 3][arow] = a0.w;
        As[acol + 4][arow] = a1.x;
        As[acol + 5][arow] = a1.y;
        As[acol + 6][arow] = a1.z;
        As[acol + 7][arow] = a1.w;
        *(float4*)&Bs[brow][bcol] = bv;
        __syncthreads();

        // 3 nontemporal zero-stores per iter, hidden under the FMAs below
        __builtin_nontemporal_store(z4, Z + (size_t)(zs + 0) * 256);
        __builtin_nontemporal_store(z4, Z + (size_t)(zs + 1) * 256);
        __builtin_nontemporal_store(z4, Z + (size_t)(zs + 2) * 256);
        zs += 3;

#pragma unroll
        for (int kk = 0; kk < BK; kk++) {
            float4 a4a = *(const float4*)&As[kk][ty << 3];
            float4 a4b = *(const float4*)&As[kk][(ty << 3) + 4];
            float4 b4  = *(const float4*)&Bs[kk][tx << 2];
            float a[8] = {a4a.x, a4a.y, a4a.z, a4a.w, a4b.x, a4b.y, a4b.z, a4b.w};
            float b[4] = {b4.x, b4.y, b4.z, b4.w};
#pragma unroll
            for (int i = 0; i < 8; i++)
#pragma unroll
                for (int j = 0; j < 4; j++)
                    acc[i][j] = fmaf(a[i], b[j], acc[i][j]);
        }
        __syncthreads();
    }

    const int gm = blockIdx.y * BM + (ty << 3);
    const int gn = blockIdx.x * BN + (tx << 2);
    float4 bias = *(const float4*)(b1 + gn);
#pragma unroll
    for (int i = 0; i < 8; i++) {
        float4 o;
        o.x = fmaxf(acc[i][0] + bias.x, 0.f);
        o.y = fmaxf(acc[i][1] + bias.y, 0.f);
        o.z = fmaxf(acc[i][2] + bias.z, 0.f);
        o.w = fmaxf(acc[i][3] + bias.w, 0.f);
        *(float4*)(Hout + (size_t)(gm + i) * N + gn) = o;
    }
}

// ---------------- Router: logits, softmax, top-2, flags ----------------
// One wave (64 lanes) per token. W2: (1024,8) row-major.
__global__ __launch_bounds__(256) void router_k(
    const float* __restrict__ Hbuf, const float* __restrict__ W2,
    const float* __restrict__ b2, float* __restrict__ probs_out,
    int* __restrict__ e0a, int* __restrict__ e1a,
    float* __restrict__ p0a, float* __restrict__ p1a,
    int* __restrict__ flags)
{
    const int wave  = threadIdx.x >> 6;
    const int lane  = threadIdx.x & 63;
    const int token = (blockIdx.x << 2) + wave;

    const float* hrow = Hbuf + (size_t)token * HDIM;
    float acc[8] = {0, 0, 0, 0, 0, 0, 0, 0};
#pragma unroll
    for (int k = 0; k < HDIM / 64; k++) {
        const int hidx = lane + (k << 6);
        const float hv = hrow[hidx];
        float4 wa = *(const float4*)(W2 + hidx * 8);
        float4 wb = *(const float4*)(W2 + hidx * 8 + 4);
        acc[0] = fmaf(hv, wa.x, acc[0]);
        acc[1] = fmaf(hv, wa.y, acc[1]);
        acc[2] = fmaf(hv, wa.z, acc[2]);
        acc[3] = fmaf(hv, wa.w, acc[3]);
        acc[4] = fmaf(hv, wb.x, acc[4]);
        acc[5] = fmaf(hv, wb.y, acc[5]);
        acc[6] = fmaf(hv, wb.z, acc[6]);
        acc[7] = fmaf(hv, wb.w, acc[7]);
    }
#pragma unroll
    for (int off = 32; off; off >>= 1) {
#pragma unroll
        for (int e = 0; e < 8; e++) acc[e] += __shfl_xor(acc[e], off);
    }

    if (lane == 0) {
        float logit[8];
#pragma unroll
        for (int e = 0; e < 8; e++) logit[e] = acc[e] + b2[e];
        float mx = logit[0];
#pragma unroll
        for (int e = 1; e < 8; e++) mx = fmaxf(mx, logit[e]);
        float p[8], s = 0.f;
#pragma unroll
        for (int e = 0; e < 8; e++) { p[e] = expf(logit[e] - mx); s += p[e]; }
        const float inv = 1.f / s;
#pragma unroll
        for (int e = 0; e < 8; e++) p[e] *= inv;

        float4 pa = {p[0], p[1], p[2], p[3]};
        float4 pb = {p[4], p[5], p[6], p[7]};
        *(float4*)(probs_out + (size_t)token * 8)     = pa;
        *(float4*)(probs_out + (size_t)token * 8 + 4) = pb;

        // top-2, ties -> lower index (strict > keeps first max), matches lax.top_k
        int e0 = 0; float m0 = logit[0];
#pragma unroll
        for (int e = 1; e < 8; e++) if (logit[e] > m0) { m0 = logit[e]; e0 = e; }
        int e1 = -1; float m1 = -1e30f;
#pragma unroll
        for (int e = 0; e < 8; e++) if (e != e0 && logit[e] > m1) { m1 = logit[e]; e1 = e; }

        const float ps = p[e0] + p[e1];
        e0a[token] = e0;
        e1a[token] = e1;
        p0a[token] = p[e0] / ps;
        p1a[token] = p[e1] / ps;
        atomicOr(&flags[e0], 1);
    }
}

// ---------------- scatter dispatch/combine + aux loss (block 0) ----------------
__global__ __launch_bounds__(256) void scatter_aux_k(
    const int* __restrict__ e0a, const int* __restrict__ e1a,
    const float* __restrict__ p0a, const float* __restrict__ p1a,
    const int* __restrict__ flags,
    float* __restrict__ dispatch, float* __restrict__ combine,
    const float* __restrict__ probs, float* __restrict__ auxout)
{
    const int t = blockIdx.x * 256 + threadIdx.x;
    if (t < TOKENS) {
        const int e0 = e0a[t], e1 = e1a[t];
        const size_t b0 = ((size_t)t * EDIM + e0) * CAP;      // slot 0 always
        dispatch[b0] = 1.f;
        combine[b0]  = p0a[t];
        const int s1 = flags[e1] ? 1 : 0;                     // slot: was e1 anyone's round-0 pick?
        const size_t b1 = ((size_t)t * EDIM + e1) * CAP + s1;
        dispatch[b1] = 1.f;
        combine[b1]  = p1a[t];
    }

    if (blockIdx.x == 0) {
        __shared__ float red[4][8];
        const int tid = threadIdx.x, lane = tid & 63, wave = tid >> 6;
        float acc[8] = {0, 0, 0, 0, 0, 0, 0, 0};
        for (int tt = tid; tt < TOKENS; tt += 256) {
            float4 a = *(const float4*)(probs + (size_t)tt * 8);
            float4 b = *(const float4*)(probs + (size_t)tt * 8 + 4);
            acc[0] += a.x; acc[1] += a.y; acc[2] += a.z; acc[3] += a.w;
            acc[4] += b.x; acc[5] += b.y; acc[6] += b.z; acc[7] += b.w;
        }
#pragma unroll
        for (int off = 32; off; off >>= 1)
#pragma unroll
            for (int e = 0; e < 8; e++) acc[e] += __shfl_xor(acc[e], off);
        if (lane == 0)
#pragma unroll
            for (int e = 0; e < 8; e++) red[wave][e] = acc[e];
        __syncthreads();
        if (tid == 0) {
            float aux = 0.f;
#pragma unroll
            for (int e = 0; e < 8; e++) {
                float pe = (red[0][e] + red[1][e] + red[2][e] + red[3][e]) * (1.f / TOKENS);
                aux += pe * logf(pe * (float)EDIM + 1e-9f);
            }
            *auxout = aux;
        }
    }
}

extern "C" void kernel_launch(void* const* d_in, const int* in_sizes, int n_in,
                              void* d_out, int out_size, void* d_ws, size_t ws_size,
                              hipStream_t stream)
{
    const float* X  = (const float*)d_in[0];
    const float* W1 = (const float*)d_in[1];
    const float* b1 = (const float*)d_in[2];
    const float* W2 = (const float*)d_in[3];
    const float* b2 = (const float*)d_in[4];

    float* out = (float*)d_out;
    const size_t dispN = (size_t)TOKENS * EDIM * CAP;   // 50,331,648
    float* dispatch = out;
    float* combine  = out + dispN;
    float* probs    = out + 2 * dispN;
    float* auxout   = out + 2 * dispN + (size_t)TOKENS * EDIM;

    float* hbuf = (float*)d_ws;
    char* pp = (char*)d_ws + (size_t)TOKENS * HDIM * sizeof(float);
    int*   e0a = (int*)pp;   pp += TOKENS * sizeof(int);
    int*   e1a = (int*)pp;   pp += TOKENS * sizeof(int);
    float* p0a = (float*)pp; pp += TOKENS * sizeof(float);
    float* p1a = (float*)pp; pp += TOKENS * sizeof(float);
    int*   flags = (int*)pp;

    // gemm also: zeroes dispatch+combine (nontemporal, hidden under FMAs) and flags
    gemm1_relu_fill<<<dim3(HDIM / BN, TOKENS / BM), 256, 0, stream>>>(
        X, W1, b1, hbuf, dispatch, flags);
    router_k<<<TOKENS / 4, 256, 0, stream>>>(hbuf, W2, b2, probs, e0a, e1a, p0a, p1a, flags);
    scatter_aux_k<<<TOKENS / 256, 256, 0, stream>>>(
        e0a, e1a, p0a, p1a, flags, dispatch, combine, probs, auxout);
}